// Round 10
// baseline (195.381 us; speedup 1.0000x reference)
//
#include <hip/hip_runtime.h>
#include <hip/hip_bf16.h>

#define ROWS 16384
#define C_   256
#define H1_  256
#define H2_  64
#define EPSN 1e-5f

typedef __bf16 bf16x8 __attribute__((ext_vector_type(8)));
typedef __bf16 bf16x4 __attribute__((ext_vector_type(4)));
typedef __bf16 bf16x2 __attribute__((ext_vector_type(2)));
typedef float  f32x4  __attribute__((ext_vector_type(4)));
typedef float  f32x2  __attribute__((ext_vector_type(2)));

__device__ __forceinline__ bf16x2 cvt2(float a, float b) {
#if __has_builtin(__builtin_amdgcn_cvt_pk_bf16_f32)
    return __builtin_bit_cast(bf16x2, __builtin_amdgcn_cvt_pk_bf16_f32(a, b));
#else
    bf16x2 r; r[0] = (__bf16)a; r[1] = (__bf16)b; return r;
#endif
}

// LDS-only barrier: waits ds ops (lgkmcnt) but leaves VMEM (stores/prefetch) in
// flight across the sync — avoids __syncthreads()' vmcnt(0) drain. sched_barrier
// fences keep the compiler from migrating memory ops across it (rule #18).
__device__ __forceinline__ void barrier_lgkm() {
    asm volatile("s_waitcnt lgkmcnt(0)" ::: "memory");
    __builtin_amdgcn_sched_barrier(0);
    __builtin_amdgcn_s_barrier();
    __builtin_amdgcn_sched_barrier(0);
}

// ---------------- K0: pack weights; zero partials; per-channel grid stats -----------
__global__ __launch_bounds__(256) void k0_pack(const float* __restrict__ W1,
                                               const float* __restrict__ W2,
                                               const float* __restrict__ W3,
                                               const float* __restrict__ grid,
                                               __bf16* __restrict__ W1p,
                                               __bf16* __restrict__ W2p,
                                               __bf16* __restrict__ W3p,
                                               float* __restrict__ zero_base,
                                               float* __restrict__ gm,
                                               float* __restrict__ gvv) {
    __shared__ float gl[128];
    int idx = blockIdx.x * 256 + threadIdx.x;   // 0 .. 81919
    if (idx < 65536) {
        int j = idx & 7, l = (idx >> 3) & 63, rest = idx >> 9;
        int ks = rest & 7, CT = rest >> 3;
        int k = ks * 32 + ((l >> 4) << 3) + j;
        int c = CT * 16 + (l & 15);
        W1p[idx] = (__bf16)W1[k * H1_ + c];
    } else {
        int i2 = idx - 65536;
        int j = i2 & 7, l = (i2 >> 3) & 63, rest = i2 >> 9;
        int ks = rest & 7, CK = rest >> 3;
        int k = ks * 32 + ((l >> 4) << 3) + j;
        int c2 = CK * 16 + (l & 15);
        W2p[i2] = (__bf16)W2[k * H2_ + c2];
    }
    if (idx < 1024) {
        int j = idx & 7, l = (idx >> 3) & 63, ks = idx >> 9;
        int k = ks * 32 + ((l >> 4) << 3) + j;
        int c = l & 15;
        W3p[idx] = (c < 3) ? (__bf16)W3[k * 3 + c] : (__bf16)0.f;
    }
    if (idx < 24576) zero_base[idx] = 0.0f;     // p1s,p1q,p2s,p2q contiguous
    if (blockIdx.x == 0) {
        int t = threadIdx.x;
        if (t < 128) gl[t] = grid[t];
        __syncthreads();
        float wx = W1[C_ * H1_ + t];
        float wy = W1[(C_ + 1) * H1_ + t];
        float mg = 0.f, qg = 0.f;
#pragma unroll
        for (int n = 0; n < 64; ++n) {
            float gv = gl[2 * n] * wx + gl[2 * n + 1] * wy;
            mg += gv; qg = fmaf(gv, gv, qg);
        }
        mg *= (1.f / 64.f);
        gm[t] = mg;
        gvv[t] = qg * (1.f / 64.f) - mg * mg;
    }
}

// ---------------- shared staging helpers --------------------------------------------
// All A_ writes/reads at compile-time indices; callers derive ax0/ax1/ay4 selects.
__device__ __forceinline__ void prep_ctx(const float* __restrict__ grid,
                                         const float* __restrict__ W1,
                                         const float* __restrict__ a1p, int c0,
                                         f32x2* wgx2, f32x2* wgy2, float* A_) {
#pragma unroll
    for (int j = 0; j < 8; ++j) A_[j] = grid[2 * j + 1];
    f32x4 a0 = *(const f32x4*)(a1p + c0), a1h = *(const f32x4*)(a1p + c0 + 4);
    f32x4 x0 = *(const f32x4*)(W1 + C_ * H1_ + c0), x1 = *(const f32x4*)(W1 + C_ * H1_ + c0 + 4);
    f32x4 y0 = *(const f32x4*)(W1 + (C_ + 1) * H1_ + c0), yh = *(const f32x4*)(W1 + (C_ + 1) * H1_ + c0 + 4);
    float av[8] = {a0[0], a0[1], a0[2], a0[3], a1h[0], a1h[1], a1h[2], a1h[3]};
    float wx[8] = {x0[0], x0[1], x0[2], x0[3], x1[0], x1[1], x1[2], x1[3]};
    float wy[8] = {y0[0], y0[1], y0[2], y0[3], yh[0], yh[1], yh[2], yh[3]};
#pragma unroll
    for (int e = 0; e < 4; ++e) {
        wgx2[e][0] = av[2 * e] * wx[2 * e];     wgx2[e][1] = av[2 * e + 1] * wx[2 * e + 1];
        wgy2[e][0] = av[2 * e] * wy[2 * e];     wgy2[e][1] = av[2 * e + 1] * wy[2 * e + 1];
    }
}

// stage this wave's 16 n-rows of y1 into LDS.
// y1 layout: [64 rows][256 ch] bf16, 16B-chunk XOR swizzle: chunk' = chunk ^ (n&7).
// Scratch-free rewrite (rule #20): a1/d1 vectors preloaded by caller; grid coefs
// passed as const-selected scalars (ax0/ax1 for ih, ay4[kk] pre-selected by nh).
// n = nbase + ih*8 + 2*kk where nbase = w*16 + nh; n&7 == nh+2*kk == old iy.
__device__ __forceinline__ void stage16(__bf16* __restrict__ y1, int nbase, int c0,
                                        f32x4 a0, f32x4 a1h, f32x4 d0, f32x4 d1h,
                                        const f32x2* wgx2, const f32x2* wgy2,
                                        float ax0, float ax1, f32x4 ay4,
                                        f32x4 t0, f32x4 t1) {
    int chunk = c0 >> 3;   // 0..31
    f32x2 base2[4];
    base2[0][0] = fmaf(a0[0], t0[0], d0[0]);  base2[0][1] = fmaf(a0[1], t0[1], d0[1]);
    base2[1][0] = fmaf(a0[2], t0[2], d0[2]);  base2[1][1] = fmaf(a0[3], t0[3], d0[3]);
    base2[2][0] = fmaf(a1h[0], t1[0], d1h[0]); base2[2][1] = fmaf(a1h[1], t1[1], d1h[1]);
    base2[3][0] = fmaf(a1h[2], t1[2], d1h[2]); base2[3][1] = fmaf(a1h[3], t1[3], d1h[3]);
#pragma unroll
    for (int ih = 0; ih < 2; ++ih) {
        float axs = ih ? ax1 : ax0;
        f32x2 ax2 = {axs, axs};
        f32x2 tc2[4];
#pragma unroll
        for (int e = 0; e < 4; ++e) tc2[e] = __builtin_elementwise_fma(wgx2[e], ax2, base2[e]);
#pragma unroll
        for (int kk = 0; kk < 4; ++kk) {
            float ays = ay4[kk];                 // const index ✓
            f32x2 ay2 = {ays, ays};
            f32x2 z = {0.f, 0.f};
            int n = nbase + ih * 8 + 2 * kk;
            bf16x8 out;
            bf16x2* o2 = (bf16x2*)&out;
#pragma unroll
            for (int e = 0; e < 4; ++e) {
                f32x2 v = __builtin_elementwise_max(
                    __builtin_elementwise_fma(wgy2[e], ay2, tc2[e]), z);
                o2[e] = cvt2(v[0], v[1]);
            }
            *(bf16x8*)(&y1[n * 256 + ((chunk ^ (n & 7)) << 3)]) = out;
        }
    }
}

// ---------------- K1a: tokpart = tokens @ W1[:C] ; per-channel stats ; coarse -------
__global__ __launch_bounds__(256) void k1a(const float* __restrict__ tokens,
                                           const __bf16* __restrict__ W1p,
                                           const float* __restrict__ Wc,
                                           const float* __restrict__ bc,
                                           float* __restrict__ tokpart,
                                           float* __restrict__ coarse,
                                           float* __restrict__ p1s,
                                           float* __restrict__ p1q) {
    __shared__ __align__(16) __bf16 Al[16 * 264];
    int t = threadIdx.x, w = t >> 6, l = t & 63;
    int quad = l >> 4, col = l & 15;
    int rowbase = (blockIdx.x >> 1) * 16;
    int colhalf = blockIdx.x & 1;
    int slot = blockIdx.x & 31;

    bf16x8 bfr[16];
#pragma unroll
    for (int ctl = 0; ctl < 2; ++ctl)
#pragma unroll
        for (int ks = 0; ks < 8; ++ks) {
            int CT = colhalf * 8 + w * 2 + ctl;
            bfr[ctl * 8 + ks] = *(const bf16x8*)(W1p + (((CT * 8 + ks) * 64 + l) * 8));
        }
    {
        int r = t >> 4, cb = (t & 15) * 16;
        const float* src = tokens + (size_t)(rowbase + r) * C_ + cb;
        f32x4 t0 = *(const f32x4*)(src);
        f32x4 t1 = *(const f32x4*)(src + 4);
        f32x4 t2 = *(const f32x4*)(src + 8);
        f32x4 t3 = *(const f32x4*)(src + 12);
        bf16x8 v0, v1;
        bf16x2* p0 = (bf16x2*)&v0; bf16x2* p1 = (bf16x2*)&v1;
        p0[0] = cvt2(t0[0], t0[1]); p0[1] = cvt2(t0[2], t0[3]);
        p0[2] = cvt2(t1[0], t1[1]); p0[3] = cvt2(t1[2], t1[3]);
        p1[0] = cvt2(t2[0], t2[1]); p1[1] = cvt2(t2[2], t2[3]);
        p1[2] = cvt2(t3[0], t3[1]); p1[3] = cvt2(t3[2], t3[3]);
        *(bf16x8*)(&Al[r * 264 + cb]) = v0;
        *(bf16x8*)(&Al[r * 264 + cb + 8]) = v1;
    }
    barrier_lgkm();   // LDS-only dependency; weight loads stay in flight

    bf16x8 af[8];
#pragma unroll
    for (int ks = 0; ks < 8; ++ks)
        af[ks] = *(const bf16x8*)(&Al[col * 264 + ks * 32 + quad * 8]);

#pragma unroll
    for (int ctl = 0; ctl < 2; ++ctl) {
        f32x4 acc = {0.f, 0.f, 0.f, 0.f};
#pragma unroll
        for (int ks = 0; ks < 8; ++ks)
            acc = __builtin_amdgcn_mfma_f32_16x16x32_bf16(af[ks], bfr[ctl * 8 + ks], acc, 0, 0, 0);
        int c = colhalf * 128 + w * 32 + ctl * 16 + col;
        float s = 0.f, q = 0.f;
#pragma unroll
        for (int rr = 0; rr < 4; ++rr) {
            float v = acc[rr];
            tokpart[(size_t)(rowbase + quad * 4 + rr) * C_ + c] = v;
            s += v; q += v * v;
        }
        s += __shfl_xor(s, 16, 64); s += __shfl_xor(s, 32, 64);
        q += __shfl_xor(q, 16, 64); q += __shfl_xor(q, 32, 64);
        if (l < 16) {
            int cc = colhalf * 128 + w * 32 + ctl * 16 + l;
            atomicAdd(p1s + slot * C_ + cc, s);
            atomicAdd(p1q + slot * C_ + cc, q);
        }
    }
    // coarse (only one colhalf does it): wave w -> rows w*4..w*4+3, lane l -> ch l*4..+4
    if (colhalf == 0) {
        const f32x4* wcp = (const f32x4*)(Wc + l * 12);
        f32x4 wa = wcp[0], wb = wcp[1], wv = wcp[2];
        float wcl[12] = {wa[0], wa[1], wa[2], wa[3], wb[0], wb[1], wb[2], wb[3],
                         wv[0], wv[1], wv[2], wv[3]};
#pragma unroll
        for (int rr = 0; rr < 4; ++rr) {
            int r = w * 4 + rr;
            bf16x4 tv4 = *(const bf16x4*)(&Al[r * 264 + l * 4]);
            float p[3] = {0.f, 0.f, 0.f};
#pragma unroll
            for (int i = 0; i < 4; ++i) {
                float tvf = (float)tv4[i];
#pragma unroll
                for (int j = 0; j < 3; ++j) p[j] = fmaf(tvf, wcl[i * 3 + j], p[j]);
            }
#pragma unroll
            for (int off = 1; off < 64; off <<= 1)
#pragma unroll
                for (int j = 0; j < 3; ++j) p[j] += __shfl_xor(p[j], off, 64);
            if (l == 0) {
#pragma unroll
                for (int j = 0; j < 3; ++j)
                    coarse[(size_t)(rowbase + r) * 3 + j] = p[j] + bc[j];
            }
        }
    }
}

// ---------------- K1b: BN1 params (uses k0's grid stats) ----------------------------
__global__ void k1b(const float* __restrict__ gm, const float* __restrict__ gvv,
                    const float* __restrict__ gamma1, const float* __restrict__ beta1,
                    const float* __restrict__ p1s, const float* __restrict__ p1q,
                    float* __restrict__ a1o, float* __restrict__ d1o) {
    int t = threadIdx.x;
    float S = 0.f, Q = 0.f;
#pragma unroll 8
    for (int s = 0; s < 32; ++s) { S += p1s[s * C_ + t]; Q += p1q[s * C_ + t]; }
    float mean_t = S / (float)ROWS;
    float var_t = Q / (float)ROWS - mean_t * mean_t;
    float a1 = gamma1[t] * rsqrtf(var_t + gvv[t] + EPSN);
    a1o[t] = a1;
    d1o[t] = beta1[t] - a1 * (mean_t + gm[t]);
}

// ---------------- K2: double-buffered y1, ONE lgkm barrier per iteration ------------
// h2s layout (fragment order, matches k3s): row*4096 + ((wn*2+rt)*4 + wc*2+ck)*256 + l*4
template <bool SPILL>
__global__ __launch_bounds__(256) void k2(const float* __restrict__ tokpart,
                                          const float* __restrict__ grid,
                                          const float* __restrict__ W1,
                                          const __bf16* __restrict__ W2p,
                                          const float* __restrict__ a1,
                                          const float* __restrict__ d1,
                                          float* __restrict__ p2s,
                                          float* __restrict__ p2q,
                                          __bf16* __restrict__ h2s) {
    __shared__ __align__(16) __bf16 y1[2][64 * 256];   // 65536 B double buffer
    int t = threadIdx.x, w = t >> 6, l = t & 63;
    int quad = l >> 4, col = l & 15;
    int wn = w >> 1, wc = w & 1;
    int c0 = (l & 31) * 8, nh = l >> 5;
    int sw = col & 7;

    bf16x8 bfr[16];
#pragma unroll
    for (int ck = 0; ck < 2; ++ck)
#pragma unroll
        for (int ks = 0; ks < 8; ++ks)
            bfr[ck * 8 + ks] = *(const bf16x8*)(W2p + ((((wc * 2 + ck) * 8 + ks) * 64 + l) * 8));

    f32x2 wgx2[4], wgy2[4]; float A_[8];
    prep_ctx(grid, W1, a1, c0, wgx2, wgy2, A_);

    // scratch-free grid-coef selects (all A_ reads const-indexed; w uniform, nh lane)
    float ax0 = (w & 2) ? ((w & 1) ? A_[6] : A_[4]) : ((w & 1) ? A_[2] : A_[0]);
    float ax1 = (w & 2) ? ((w & 1) ? A_[7] : A_[5]) : ((w & 1) ? A_[3] : A_[1]);
    f32x4 ay4;
    ay4[0] = nh ? A_[1] : A_[0];
    ay4[1] = nh ? A_[3] : A_[2];
    ay4[2] = nh ? A_[5] : A_[4];
    ay4[3] = nh ? A_[7] : A_[6];
    int nbase = w * 16 + nh;

    // hoist per-channel BN1 vectors out of stage16 (row-invariant)
    f32x4 va0 = *(const f32x4*)(a1 + c0), va1h = *(const f32x4*)(a1 + c0 + 4);
    f32x4 vd0 = *(const f32x4*)(d1 + c0), vd1h = *(const f32x4*)(d1 + c0 + 4);

    float s[2][4] = {}, q[2][4] = {};

    const float* tokbase = tokpart + (size_t)blockIdx.x * 8 * C_;
    // prologue: stage row 0 into buf0; then t0/t1 <- row 1
    {
        f32x4 p0 = *(const f32x4*)(tokbase + c0);
        f32x4 p1 = *(const f32x4*)(tokbase + c0 + 4);
        stage16(&y1[0][0], nbase, c0, va0, va1h, vd0, vd1h, wgx2, wgy2, ax0, ax1, ay4, p0, p1);
    }
    f32x4 t0 = *(const f32x4*)(tokbase + C_ + c0);
    f32x4 t1 = *(const f32x4*)(tokbase + C_ + c0 + 4);
    barrier_lgkm();

#pragma unroll 1
    for (int r8 = 0; r8 < 8; ++r8) {
        int row = blockIdx.x * 8 + r8;
        int cur = r8 & 1;
        // prefetch row r8+2 tok slice (consumed by next iteration's stage)
        int nr = (r8 < 6) ? (r8 + 2) : 7;
        f32x4 n0 = *(const f32x4*)(tokbase + (size_t)nr * C_ + c0);
        f32x4 n1 = *(const f32x4*)(tokbase + (size_t)nr * C_ + c0 + 4);

#pragma unroll
        for (int rt = 0; rt < 2; ++rt) {
            int rowb = (wn * 32 + rt * 16 + col) * 256;
            bf16x8 af[8];
#pragma unroll
            for (int ks = 0; ks < 8; ++ks)
                af[ks] = *(const bf16x8*)(&y1[cur][rowb + (((ks * 4 + quad) ^ sw) << 3)]);
#pragma unroll
            for (int ck = 0; ck < 2; ++ck) {
                f32x4 acc = {0.f, 0.f, 0.f, 0.f};
#pragma unroll
                for (int ks = 0; ks < 8; ++ks)
                    acc = __builtin_amdgcn_mfma_f32_16x16x32_bf16(bfr[ck * 8 + ks], af[ks], acc, 0, 0, 0);
#pragma unroll
                for (int rr = 0; rr < 4; ++rr) {
                    s[ck][rr] += acc[rr];
                    q[ck][rr] += acc[rr] * acc[rr];
                }
                if constexpr (SPILL) {
                    bf16x4 v; bf16x2* v2 = (bf16x2*)&v;
                    v2[0] = cvt2(acc[0], acc[1]);
                    v2[1] = cvt2(acc[2], acc[3]);
                    *(bf16x4*)(h2s + (size_t)row * 4096 +
                               ((wn * 2 + rt) * 4 + wc * 2 + ck) * 256 + l * 4) = v;
                }
            }
        }
        // stage next row into the other buffer — overlaps with MFMAs above.
        if (r8 < 7)
            stage16(&y1[cur ^ 1][0], nbase, c0, va0, va1h, vd0, vd1h,
                    wgx2, wgy2, ax0, ax1, ay4, t0, t1);
        barrier_lgkm();   // buf[cur^1] fully staged; everyone done reading buf[cur]
        t0 = n0; t1 = n1;
    }
    int slot = ((blockIdx.x << 1) | wn) & 63;
#pragma unroll
    for (int ck = 0; ck < 2; ++ck)
#pragma unroll
        for (int rr = 0; rr < 4; ++rr) {
            float sv = s[ck][rr], qv = q[ck][rr];
            sv += __shfl_xor(sv, 1, 64); sv += __shfl_xor(sv, 2, 64);
            sv += __shfl_xor(sv, 4, 64); sv += __shfl_xor(sv, 8, 64);
            qv += __shfl_xor(qv, 1, 64); qv += __shfl_xor(qv, 2, 64);
            qv += __shfl_xor(qv, 4, 64); qv += __shfl_xor(qv, 8, 64);
            if (col == 0) {
                int c2 = wc * 32 + ck * 16 + quad * 4 + rr;
                atomicAdd(p2s + slot * H2_ + c2, sv);
                atomicAdd(p2q + slot * H2_ + c2, qv);
            }
        }
}

// ---------------- K2b: BN2 params (raw-acc stats; b2 cancels) -----------------------
__global__ void k2b(const float* __restrict__ p2s, const float* __restrict__ p2q,
                    const float* __restrict__ gamma2, const float* __restrict__ beta2,
                    float* __restrict__ a2o, float* __restrict__ d2o) {
    int t = threadIdx.x;
    float S = 0.f, Q = 0.f;
#pragma unroll 8
    for (int s = 0; s < 64; ++s) { S += p2s[s * H2_ + t]; Q += p2q[s * H2_ + t]; }
    const float invN = 1.f / ((float)ROWS * 64.f);
    float mean = S * invN;
    float var = Q * invN - mean * mean;
    float a2 = gamma2[t] * rsqrtf(var + EPSN);
    a2o[t] = a2;
    d2o[t] = beta2[t] - a2 * mean;
}

// ---------------- K3 (spill path): barrier-free wave-private tiles (round-5) --------
__global__ __launch_bounds__(256) void k3s(const __bf16* __restrict__ h2s,
                                           const float* __restrict__ a2,
                                           const float* __restrict__ d2p,
                                           const __bf16* __restrict__ W3p,
                                           const float* __restrict__ b3,
                                           const float* __restrict__ coarse,
                                           float* __restrict__ fine) {
    __shared__ __align__(16) __bf16 y2l[4][16 * 64];    // 8192 B (per-wave 2 KB)
    __shared__ __align__(16) float finebuf[8 * 192];    // 6144 B
    int t = threadIdx.x, w = t >> 6, l = t & 63;
    int quad = l >> 4, col = l & 15;
    int sw = col & 7;

    bf16x8 wfr[2];
#pragma unroll
    for (int ks = 0; ks < 2; ++ks)
        wfr[ks] = *(const bf16x8*)(W3p + ((ks * 64 + l) * 8));

    float a2v[16], d2v[16];
#pragma unroll
    for (int ck = 0; ck < 4; ++ck)
#pragma unroll
        for (int rr = 0; rr < 4; ++rr) {
            int c2 = ck * 16 + quad * 4 + rr;
            a2v[ck * 4 + rr] = a2[c2];
            d2v[ck * 4 + rr] = d2p[c2];
        }
    float b3v = (col < 3) ? b3[col] : 0.f;
    __bf16* yw = &y2l[w][0];

#pragma unroll 1
    for (int r8 = 0; r8 < 8; ++r8) {
        int row = blockIdx.x * 8 + r8;
        const __bf16* src = h2s + (size_t)row * 4096 + l * 4;
        bf16x4 u[4];
#pragma unroll
        for (int ck = 0; ck < 4; ++ck)
            u[ck] = *(const bf16x4*)(src + (w * 4 + ck) * 256);
#pragma unroll
        for (int ck = 0; ck < 4; ++ck) {
            float y0 = fmaxf(fmaf(a2v[ck * 4 + 0], (float)u[ck][0], d2v[ck * 4 + 0]), 0.f);
            float y1v = fmaxf(fmaf(a2v[ck * 4 + 1], (float)u[ck][1], d2v[ck * 4 + 1]), 0.f);
            float y2 = fmaxf(fmaf(a2v[ck * 4 + 2], (float)u[ck][2], d2v[ck * 4 + 2]), 0.f);
            float y3 = fmaxf(fmaf(a2v[ck * 4 + 3], (float)u[ck][3], d2v[ck * 4 + 3]), 0.f);
            bf16x4 v; bf16x2* v2 = (bf16x2*)&v;
            v2[0] = cvt2(y0, y1v); v2[1] = cvt2(y2, y3);
            int chunk = ck * 2 + (quad >> 1);
            *(bf16x4*)(&yw[col * 64 + ((chunk ^ sw) << 3) + (quad & 1) * 4]) = v;
        }
        // same-wave lgkm ordering; no barrier
        bf16x8 af2[2];
#pragma unroll
        for (int ks = 0; ks < 2; ++ks)
            af2[ks] = *(const bf16x8*)(&yw[col * 64 + (((ks * 4 + quad) ^ sw) << 3)]);
        f32x4 acc = {0.f, 0.f, 0.f, 0.f};
        acc = __builtin_amdgcn_mfma_f32_16x16x32_bf16(af2[0], wfr[0], acc, 0, 0, 0);
        acc = __builtin_amdgcn_mfma_f32_16x16x32_bf16(af2[1], wfr[1], acc, 0, 0, 0);
        if (col < 3) {
            float cj = coarse[row * 3 + col] + b3v;
#pragma unroll
            for (int rr = 0; rr < 4; ++rr)
                finebuf[r8 * 192 + (w * 16 + quad * 4 + rr) * 3 + col] = acc[rr] + cj;
        }
    }
    __syncthreads();
    {
        float* dst = fine + (size_t)blockIdx.x * 1536;
        const f32x4* fb = (const f32x4*)finebuf;
        *(f32x4*)(dst + 4 * t) = fb[t];
        if (t < 128) *(f32x4*)(dst + 1024 + 4 * t) = fb[256 + t];
    }
}

// ---------------- K3 (fallback): recompute y1 + GEMM2, BN2+ReLU, GEMM3, fine --------
__global__ __launch_bounds__(256) void k3r(const float* __restrict__ tokpart,
                                           const float* __restrict__ grid,
                                           const float* __restrict__ W1,
                                           const __bf16* __restrict__ W2p,
                                           const float* __restrict__ a1,
                                           const float* __restrict__ d1,
                                           const __bf16* __restrict__ W3p,
                                           const float* __restrict__ a2,
                                           const float* __restrict__ d2p,
                                           const float* __restrict__ b3,
                                           const float* __restrict__ coarse,
                                           float* __restrict__ fine) {
    __shared__ __align__(16) __bf16 y1[64 * 256];
    __shared__ __align__(16) __bf16 y2l[64 * 72];
    __shared__ __align__(16) float finebuf[8 * 192];
    int t = threadIdx.x, w = t >> 6, l = t & 63;
    int quad = l >> 4, col = l & 15;
    int wn = w >> 1, wc = w & 1;
    int c0 = (l & 31) * 8, nh = l >> 5;
    int sw = col & 7;

    bf16x8 bfr[16];
#pragma unroll
    for (int ck = 0; ck < 2; ++ck)
#pragma unroll
        for (int ks = 0; ks < 8; ++ks)
            bfr[ck * 8 + ks] = *(const bf16x8*)(W2p + ((((wc * 2 + ck) * 8 + ks) * 64 + l) * 8));
    bf16x8 wfr[2];
#pragma unroll
    for (int ks = 0; ks < 2; ++ks)
        wfr[ks] = *(const bf16x8*)(W3p + ((ks * 64 + l) * 8));

    f32x2 wgx2[4], wgy2[4]; float A_[8];
    prep_ctx(grid, W1, a1, c0, wgx2, wgy2, A_);

    float ax0 = (w & 2) ? ((w & 1) ? A_[6] : A_[4]) : ((w & 1) ? A_[2] : A_[0]);
    float ax1 = (w & 2) ? ((w & 1) ? A_[7] : A_[5]) : ((w & 1) ? A_[3] : A_[1]);
    f32x4 ay4;
    ay4[0] = nh ? A_[1] : A_[0];
    ay4[1] = nh ? A_[3] : A_[2];
    ay4[2] = nh ? A_[5] : A_[4];
    ay4[3] = nh ? A_[7] : A_[6];
    int nbase = w * 16 + nh;

    f32x4 va0 = *(const f32x4*)(a1 + c0), va1h = *(const f32x4*)(a1 + c0 + 4);
    f32x4 vd0 = *(const f32x4*)(d1 + c0), vd1h = *(const f32x4*)(d1 + c0 + 4);

    float a2v[8], d2v[8];
#pragma unroll
    for (int ck = 0; ck < 2; ++ck)
#pragma unroll
        for (int rr = 0; rr < 4; ++rr) {
            int c2 = wc * 32 + ck * 16 + quad * 4 + rr;
            a2v[ck * 4 + rr] = a2[c2];
            d2v[ck * 4 + rr] = d2p[c2];
        }
    float b3v = (col < 3) ? b3[col] : 0.f;

    const float* tokbase = tokpart + (size_t)blockIdx.x * 8 * C_;
    f32x4 t0 = *(const f32x4*)(tokbase + c0);
    f32x4 t1 = *(const f32x4*)(tokbase + c0 + 4);

#pragma unroll 1
    for (int r8 = 0; r8 < 8; ++r8) {
        int row = blockIdx.x * 8 + r8;
        int nr = (r8 < 7) ? (r8 + 1) : 7;
        f32x4 n0 = *(const f32x4*)(tokbase + (size_t)nr * C_ + c0);
        f32x4 n1 = *(const f32x4*)(tokbase + (size_t)nr * C_ + c0 + 4);

        stage16(y1, nbase, c0, va0, va1h, vd0, vd1h, wgx2, wgy2, ax0, ax1, ay4, t0, t1);
        barrier_lgkm();
#pragma unroll
        for (int rt = 0; rt < 2; ++rt) {
            int rowb = (wn * 32 + rt * 16 + col) * 256;
            bf16x8 af[8];
#pragma unroll
            for (int ks = 0; ks < 8; ++ks)
                af[ks] = *(const bf16x8*)(&y1[rowb + (((ks * 4 + quad) ^ sw) << 3)]);
#pragma unroll
            for (int ck = 0; ck < 2; ++ck) {
                f32x4 acc = {0.f, 0.f, 0.f, 0.f};
#pragma unroll
                for (int ks = 0; ks < 8; ++ks)
                    acc = __builtin_amdgcn_mfma_f32_16x16x32_bf16(bfr[ck * 8 + ks], af[ks], acc, 0, 0, 0);
                bf16x4 v; bf16x2* v2 = (bf16x2*)&v;
                float y0 = fmaxf(fmaf(a2v[ck * 4 + 0], acc[0], d2v[ck * 4 + 0]), 0.f);
                float y1v = fmaxf(fmaf(a2v[ck * 4 + 1], acc[1], d2v[ck * 4 + 1]), 0.f);
                float y2 = fmaxf(fmaf(a2v[ck * 4 + 2], acc[2], d2v[ck * 4 + 2]), 0.f);
                float y3 = fmaxf(fmaf(a2v[ck * 4 + 3], acc[3], d2v[ck * 4 + 3]), 0.f);
                v2[0] = cvt2(y0, y1v); v2[1] = cvt2(y2, y3);
                *(bf16x4*)(&y2l[(wn * 32 + rt * 16 + col) * 72 + wc * 32 + ck * 16 + quad * 4]) = v;
            }
        }
        barrier_lgkm();
        bf16x8 af2[2];
#pragma unroll
        for (int ks = 0; ks < 2; ++ks)
            af2[ks] = *(const bf16x8*)(&y2l[(w * 16 + col) * 72 + ks * 32 + quad * 8]);
        f32x4 d2acc = {0.f, 0.f, 0.f, 0.f};
        d2acc = __builtin_amdgcn_mfma_f32_16x16x32_bf16(af2[0], wfr[0], d2acc, 0, 0, 0);
        d2acc = __builtin_amdgcn_mfma_f32_16x16x32_bf16(af2[1], wfr[1], d2acc, 0, 0, 0);
        if (col < 3) {
            float cj = coarse[row * 3 + col] + b3v;
#pragma unroll
            for (int rr = 0; rr < 4; ++rr)
                finebuf[r8 * 192 + (w * 16 + quad * 4 + rr) * 3 + col] = d2acc[rr] + cj;
        }
        barrier_lgkm();
        t0 = n0; t1 = n1;
    }
    {
        float* dst = fine + (size_t)blockIdx.x * 1536;
        const f32x4* fb = (const f32x4*)finebuf;
        *(f32x4*)(dst + 4 * t) = fb[t];
        if (t < 128) *(f32x4*)(dst + 1024 + 4 * t) = fb[256 + t];
    }
}

// ---------------- host launcher -----------------------------------------------------
extern "C" void kernel_launch(void* const* d_in, const int* in_sizes, int n_in,
                              void* d_out, int out_size, void* d_ws, size_t ws_size,
                              hipStream_t stream) {
    (void)in_sizes; (void)n_in; (void)out_size;
    const float* tokens = (const float*)d_in[0];
    const float* grid   = (const float*)d_in[1];
    const float* Wc     = (const float*)d_in[2];
    const float* bc     = (const float*)d_in[3];
    const float* W1     = (const float*)d_in[4];
    const float* gamma1 = (const float*)d_in[6];
    const float* beta1  = (const float*)d_in[7];
    const float* W2     = (const float*)d_in[8];
    const float* gamma2 = (const float*)d_in[10];
    const float* beta2  = (const float*)d_in[11];
    const float* W3     = (const float*)d_in[12];
    const float* b3     = (const float*)d_in[13];

    char* ws = (char*)d_ws;
    __bf16* W1p     = (__bf16*)(ws);                     // 131072 B
    __bf16* W2p     = (__bf16*)(ws + 131072);            //  32768 B
    float*  p1s     = (float*)(ws + 163840);             //  32768 B (zeroed by k0)
    float*  p1q     = (float*)(ws + 196608);             //  32768 B (zeroed by k0)
    float*  p2s     = (float*)(ws + 229376);             //  16384 B (zeroed by k0)
    float*  p2q     = (float*)(ws + 245760);             //  16384 B (zeroed by k0)
    float*  a1      = (float*)(ws + 262144);             //   1024 B
    float*  d1      = (float*)(ws + 263168);             //   1024 B
    float*  a2      = (float*)(ws + 264192);             //    256 B
    float*  d2p     = (float*)(ws + 264448);             //    256 B
    __bf16* W3p     = (__bf16*)(ws + 264704);            //   2048 B
    float*  gm      = (float*)(ws + 266752);             //   1024 B
    float*  gvv     = (float*)(ws + 267776);             //   1024 B
    float*  tokpart = (float*)(ws + 268800);             // 16777216 B
    __bf16* h2s     = (__bf16*)(ws + 17046016);          // 134217728 B (if it fits)

    const size_t SPILL_NEED = 17046016ull + 134217728ull;  // 151263744
    bool spill = ws_size >= SPILL_NEED;

    float* coarse = (float*)d_out;
    float* fine   = (float*)d_out + (size_t)ROWS * 3;

    k0_pack<<<320, 256, 0, stream>>>(W1, W2, W3, grid, W1p, W2p, W3p, p1s, gm, gvv);
    k1a<<<2048, 256, 0, stream>>>(tokens, W1p, Wc, bc, tokpart, coarse, p1s, p1q);
    k1b<<<1, 256, 0, stream>>>(gm, gvv, gamma1, beta1, p1s, p1q, a1, d1);
    if (spill) {
        k2<true><<<ROWS / 8, 256, 0, stream>>>(tokpart, grid, W1, W2p, a1, d1,
                                               p2s, p2q, h2s);
        k2b<<<1, 64, 0, stream>>>(p2s, p2q, gamma2, beta2, a2, d2p);
        k3s<<<ROWS / 8, 256, 0, stream>>>(h2s, a2, d2p, W3p, b3, coarse, fine);
    } else {
        k2<false><<<ROWS / 8, 256, 0, stream>>>(tokpart, grid, W1, W2p, a1, d1,
                                                p2s, p2q, h2s);
        k2b<<<1, 64, 0, stream>>>(p2s, p2q, gamma2, beta2, a2, d2p);
        k3r<<<ROWS / 8, 256, 0, stream>>>(tokpart, grid, W1, W2p, a1, d1,
                                          W3p, a2, d2p, b3, coarse, fine);
    }
}

// Round 11
// 191.144 us; speedup vs baseline: 1.0222x; 1.0222x over previous
//
#include <hip/hip_runtime.h>
#include <hip/hip_bf16.h>

#define ROWS 16384
#define C_   256
#define H1_  256
#define H2_  64
#define EPSN 1e-5f

typedef __bf16 bf16x8 __attribute__((ext_vector_type(8)));
typedef __bf16 bf16x4 __attribute__((ext_vector_type(4)));
typedef __bf16 bf16x2 __attribute__((ext_vector_type(2)));
typedef float  f32x4  __attribute__((ext_vector_type(4)));
typedef float  f32x2  __attribute__((ext_vector_type(2)));

__device__ __forceinline__ bf16x2 cvt2(float a, float b) {
#if __has_builtin(__builtin_amdgcn_cvt_pk_bf16_f32)
    return __builtin_bit_cast(bf16x2, __builtin_amdgcn_cvt_pk_bf16_f32(a, b));
#else
    bf16x2 r; r[0] = (__bf16)a; r[1] = (__bf16)b; return r;
#endif
}

// LDS-only barrier: waits ds ops (lgkmcnt) but leaves VMEM (stores/prefetch) in
// flight across the sync — avoids __syncthreads()' vmcnt(0) drain. sched_barrier
// fences keep the compiler from migrating memory ops across it (rule #18).
__device__ __forceinline__ void barrier_lgkm() {
    asm volatile("s_waitcnt lgkmcnt(0)" ::: "memory");
    __builtin_amdgcn_sched_barrier(0);
    __builtin_amdgcn_s_barrier();
    __builtin_amdgcn_sched_barrier(0);
}

// ---------------- K0: pack weights (W1/W2/W3/Wc); zero partials; grid stats ---------
__global__ __launch_bounds__(256) void k0_pack(const float* __restrict__ W1,
                                               const float* __restrict__ W2,
                                               const float* __restrict__ W3,
                                               const float* __restrict__ Wc,
                                               const float* __restrict__ grid,
                                               __bf16* __restrict__ W1p,
                                               __bf16* __restrict__ W2p,
                                               __bf16* __restrict__ W3p,
                                               __bf16* __restrict__ Wcp,
                                               float* __restrict__ zero_base,
                                               float* __restrict__ gm,
                                               float* __restrict__ gvv) {
    __shared__ float gl[128];
    int idx = blockIdx.x * 256 + threadIdx.x;   // 0 .. 81919
    if (idx < 65536) {
        int j = idx & 7, l = (idx >> 3) & 63, rest = idx >> 9;
        int ks = rest & 7, CT = rest >> 3;
        int k = ks * 32 + ((l >> 4) << 3) + j;
        int c = CT * 16 + (l & 15);
        W1p[idx] = (__bf16)W1[k * H1_ + c];
    } else {
        int i2 = idx - 65536;
        int j = i2 & 7, l = (i2 >> 3) & 63, rest = i2 >> 9;
        int ks = rest & 7, CK = rest >> 3;
        int k = ks * 32 + ((l >> 4) << 3) + j;
        int c2 = CK * 16 + (l & 15);
        W2p[i2] = (__bf16)W2[k * H2_ + c2];
    }
    if (idx < 1024) {
        int j = idx & 7, l = (idx >> 3) & 63, ks = idx >> 9;
        int k = ks * 32 + ((l >> 4) << 3) + j;
        int c = l & 15;
        W3p[idx] = (c < 3) ? (__bf16)W3[k * 3 + c] : (__bf16)0.f;
    }
    if (idx < 4096) {                       // Wcp: 256-K x 16 cols (3 real), W3p-style
        int j = idx & 7, l = (idx >> 3) & 63, ks = idx >> 9;   // ks 0..7
        int k = ks * 32 + ((l >> 4) << 3) + j;
        int c = l & 15;
        Wcp[idx] = (c < 3) ? (__bf16)Wc[k * 3 + c] : (__bf16)0.f;
    }
    if (idx < 24576) zero_base[idx] = 0.0f;     // p1s,p1q,p2s,p2q contiguous
    if (blockIdx.x == 0) {
        int t = threadIdx.x;
        if (t < 128) gl[t] = grid[t];
        __syncthreads();
        float wx = W1[C_ * H1_ + t];
        float wy = W1[(C_ + 1) * H1_ + t];
        float mg = 0.f, qg = 0.f;
#pragma unroll
        for (int n = 0; n < 64; ++n) {
            float gv = gl[2 * n] * wx + gl[2 * n + 1] * wy;
            mg += gv; qg = fmaf(gv, gv, qg);
        }
        mg *= (1.f / 64.f);
        gm[t] = mg;
        gvv[t] = qg * (1.f / 64.f) - mg * mg;
    }
}

// ---------------- shared staging helpers --------------------------------------------
// All A_ writes/reads at compile-time indices; callers derive ax0/ax1/ay4 selects.
__device__ __forceinline__ void prep_ctx(const float* __restrict__ grid,
                                         const float* __restrict__ W1,
                                         const float* __restrict__ a1p, int c0,
                                         f32x2* wgx2, f32x2* wgy2, float* A_) {
#pragma unroll
    for (int j = 0; j < 8; ++j) A_[j] = grid[2 * j + 1];
    f32x4 a0 = *(const f32x4*)(a1p + c0), a1h = *(const f32x4*)(a1p + c0 + 4);
    f32x4 x0 = *(const f32x4*)(W1 + C_ * H1_ + c0), x1 = *(const f32x4*)(W1 + C_ * H1_ + c0 + 4);
    f32x4 y0 = *(const f32x4*)(W1 + (C_ + 1) * H1_ + c0), yh = *(const f32x4*)(W1 + (C_ + 1) * H1_ + c0 + 4);
    float av[8] = {a0[0], a0[1], a0[2], a0[3], a1h[0], a1h[1], a1h[2], a1h[3]};
    float wx[8] = {x0[0], x0[1], x0[2], x0[3], x1[0], x1[1], x1[2], x1[3]};
    float wy[8] = {y0[0], y0[1], y0[2], y0[3], yh[0], yh[1], yh[2], yh[3]};
#pragma unroll
    for (int e = 0; e < 4; ++e) {
        wgx2[e][0] = av[2 * e] * wx[2 * e];     wgx2[e][1] = av[2 * e + 1] * wx[2 * e + 1];
        wgy2[e][0] = av[2 * e] * wy[2 * e];     wgy2[e][1] = av[2 * e + 1] * wy[2 * e + 1];
    }
}

// stage this wave's 16 n-rows of y1 into LDS.
// y1 layout: [64 rows][256 ch] bf16, 16B-chunk XOR swizzle: chunk' = chunk ^ (n&7).
// Scratch-free (rule #20): a1/d1 vectors preloaded by caller; grid coefs passed as
// const-selected scalars. n = nbase + ih*8 + 2*kk; n&7 == old iy.
__device__ __forceinline__ void stage16(__bf16* __restrict__ y1, int nbase, int c0,
                                        f32x4 a0, f32x4 a1h, f32x4 d0, f32x4 d1h,
                                        const f32x2* wgx2, const f32x2* wgy2,
                                        float ax0, float ax1, f32x4 ay4,
                                        f32x4 t0, f32x4 t1) {
    int chunk = c0 >> 3;   // 0..31
    f32x2 base2[4];
    base2[0][0] = fmaf(a0[0], t0[0], d0[0]);  base2[0][1] = fmaf(a0[1], t0[1], d0[1]);
    base2[1][0] = fmaf(a0[2], t0[2], d0[2]);  base2[1][1] = fmaf(a0[3], t0[3], d0[3]);
    base2[2][0] = fmaf(a1h[0], t1[0], d1h[0]); base2[2][1] = fmaf(a1h[1], t1[1], d1h[1]);
    base2[3][0] = fmaf(a1h[2], t1[2], d1h[2]); base2[3][1] = fmaf(a1h[3], t1[3], d1h[3]);
#pragma unroll
    for (int ih = 0; ih < 2; ++ih) {
        float axs = ih ? ax1 : ax0;
        f32x2 ax2 = {axs, axs};
        f32x2 tc2[4];
#pragma unroll
        for (int e = 0; e < 4; ++e) tc2[e] = __builtin_elementwise_fma(wgx2[e], ax2, base2[e]);
#pragma unroll
        for (int kk = 0; kk < 4; ++kk) {
            float ays = ay4[kk];                 // const index
            f32x2 ay2 = {ays, ays};
            f32x2 z = {0.f, 0.f};
            int n = nbase + ih * 8 + 2 * kk;
            bf16x8 out;
            bf16x2* o2 = (bf16x2*)&out;
#pragma unroll
            for (int e = 0; e < 4; ++e) {
                f32x2 v = __builtin_elementwise_max(
                    __builtin_elementwise_fma(wgy2[e], ay2, tc2[e]), z);
                o2[e] = cvt2(v[0], v[1]);
            }
            *(bf16x8*)(&y1[n * 256 + ((chunk ^ (n & 7)) << 3)]) = out;
        }
    }
}

// ---------------- K1a v2: 512 blocks x 64 rows; stage-once; MFMA coarse -------------
// Block = (group = bid>>1 -> rows group*64..+64) x (colhalf = bid&1 -> 128 channels).
// All 64 token rows staged to LDS once, ONE barrier, then 4 barrier-free iterations
// of {ds_read af, 16 MFMA (+8 coarse MFMA on colhalf 0), tokpart store, stats acc}.
// Coarse computed as Al @ Wcp via MFMA (same B-operand pattern as k3s's W3p — verified).
__global__ __launch_bounds__(256) void k1a(const float* __restrict__ tokens,
                                           const __bf16* __restrict__ W1p,
                                           const __bf16* __restrict__ Wcp,
                                           const float* __restrict__ bc,
                                           float* __restrict__ tokpart,
                                           float* __restrict__ coarse,
                                           float* __restrict__ p1s,
                                           float* __restrict__ p1q) {
    __shared__ __align__(16) __bf16 Al[64 * 264];   // 33792 B
    int t = threadIdx.x, w = t >> 6, l = t & 63;
    int quad = l >> 4, col = l & 15;
    int group = blockIdx.x >> 1;          // 0..255
    int colhalf = blockIdx.x & 1;
    int rowbase = group * 64;
    int slot = blockIdx.x & 31;

    bf16x8 bfr[16];
#pragma unroll
    for (int ctl = 0; ctl < 2; ++ctl)
#pragma unroll
        for (int ks = 0; ks < 8; ++ks) {
            int CT = colhalf * 8 + w * 2 + ctl;
            bfr[ctl * 8 + ks] = *(const bf16x8*)(W1p + (((CT * 8 + ks) * 64 + l) * 8));
        }
    bf16x8 cfr[8];
    if (colhalf == 0) {
#pragma unroll
        for (int ks = 0; ks < 8; ++ks)
            cfr[ks] = *(const bf16x8*)(Wcp + ((ks * 64 + l) * 8));
    }
    float bcv = (col < 3) ? bc[col] : 0.f;

    // stage all 64 rows of tokens (bf16) into LDS
#pragma unroll
    for (int rg = 0; rg < 4; ++rg) {
        int r = rg * 16 + (t >> 4), cb = (t & 15) * 16;
        const float* src = tokens + (size_t)(rowbase + r) * C_ + cb;
        f32x4 t0 = *(const f32x4*)(src);
        f32x4 t1 = *(const f32x4*)(src + 4);
        f32x4 t2 = *(const f32x4*)(src + 8);
        f32x4 t3 = *(const f32x4*)(src + 12);
        bf16x8 v0, v1;
        bf16x2* p0 = (bf16x2*)&v0; bf16x2* p1 = (bf16x2*)&v1;
        p0[0] = cvt2(t0[0], t0[1]); p0[1] = cvt2(t0[2], t0[3]);
        p0[2] = cvt2(t1[0], t1[1]); p0[3] = cvt2(t1[2], t1[3]);
        p1[0] = cvt2(t2[0], t2[1]); p1[1] = cvt2(t2[2], t2[3]);
        p1[2] = cvt2(t3[0], t3[1]); p1[3] = cvt2(t3[2], t3[3]);
        *(bf16x8*)(&Al[r * 264 + cb]) = v0;
        *(bf16x8*)(&Al[r * 264 + cb + 8]) = v1;
    }
    barrier_lgkm();   // only barrier in the kernel; weight loads may still be in flight
                      // (bfr/cfr consumed below via compiler-inserted vmcnt waits)

    float s[2] = {0.f, 0.f}, q[2] = {0.f, 0.f};

#pragma unroll
    for (int rg = 0; rg < 4; ++rg) {
        int rb16 = rg * 16;
        bf16x8 af[8];
#pragma unroll
        for (int ks = 0; ks < 8; ++ks)
            af[ks] = *(const bf16x8*)(&Al[(rb16 + col) * 264 + ks * 32 + quad * 8]);

#pragma unroll
        for (int ctl = 0; ctl < 2; ++ctl) {
            f32x4 acc = {0.f, 0.f, 0.f, 0.f};
#pragma unroll
            for (int ks = 0; ks < 8; ++ks)
                acc = __builtin_amdgcn_mfma_f32_16x16x32_bf16(af[ks], bfr[ctl * 8 + ks], acc, 0, 0, 0);
            int c = colhalf * 128 + w * 32 + ctl * 16 + col;
#pragma unroll
            for (int rr = 0; rr < 4; ++rr) {
                float v = acc[rr];
                tokpart[(size_t)(rowbase + rb16 + quad * 4 + rr) * C_ + c] = v;
                s[ctl] += v; q[ctl] += v * v;
            }
        }
        if (colhalf == 0) {
            f32x4 cacc = {0.f, 0.f, 0.f, 0.f};
#pragma unroll
            for (int ks = 0; ks < 8; ++ks)
                cacc = __builtin_amdgcn_mfma_f32_16x16x32_bf16(af[ks], cfr[ks], cacc, 0, 0, 0);
            if (col < 3) {
#pragma unroll
                for (int rr = 0; rr < 4; ++rr)
                    coarse[(size_t)(rowbase + rb16 + quad * 4 + rr) * 3 + col] = cacc[rr] + bcv;
            }
        }
    }

    // stats: lane holds channel c summed over its 16 rows x 4 iters; fold quads, atomics
#pragma unroll
    for (int ctl = 0; ctl < 2; ++ctl) {
        float sv = s[ctl], qv = q[ctl];
        sv += __shfl_xor(sv, 16, 64); sv += __shfl_xor(sv, 32, 64);
        qv += __shfl_xor(qv, 16, 64); qv += __shfl_xor(qv, 32, 64);
        if (l < 16) {
            int cc = colhalf * 128 + w * 32 + ctl * 16 + l;
            atomicAdd(p1s + slot * C_ + cc, sv);
            atomicAdd(p1q + slot * C_ + cc, qv);
        }
    }
}

// ---------------- K1b: BN1 params (uses k0's grid stats) ----------------------------
__global__ void k1b(const float* __restrict__ gm, const float* __restrict__ gvv,
                    const float* __restrict__ gamma1, const float* __restrict__ beta1,
                    const float* __restrict__ p1s, const float* __restrict__ p1q,
                    float* __restrict__ a1o, float* __restrict__ d1o) {
    int t = threadIdx.x;
    float S = 0.f, Q = 0.f;
#pragma unroll 8
    for (int s = 0; s < 32; ++s) { S += p1s[s * C_ + t]; Q += p1q[s * C_ + t]; }
    float mean_t = S / (float)ROWS;
    float var_t = Q / (float)ROWS - mean_t * mean_t;
    float a1 = gamma1[t] * rsqrtf(var_t + gvv[t] + EPSN);
    a1o[t] = a1;
    d1o[t] = beta1[t] - a1 * (mean_t + gm[t]);
}

// ---------------- K2: double-buffered y1, ONE lgkm barrier per iteration ------------
// h2s layout (fragment order, matches k3s): row*4096 + ((wn*2+rt)*4 + wc*2+ck)*256 + l*4
template <bool SPILL>
__global__ __launch_bounds__(256) void k2(const float* __restrict__ tokpart,
                                          const float* __restrict__ grid,
                                          const float* __restrict__ W1,
                                          const __bf16* __restrict__ W2p,
                                          const float* __restrict__ a1,
                                          const float* __restrict__ d1,
                                          float* __restrict__ p2s,
                                          float* __restrict__ p2q,
                                          __bf16* __restrict__ h2s) {
    __shared__ __align__(16) __bf16 y1[2][64 * 256];   // 65536 B double buffer
    int t = threadIdx.x, w = t >> 6, l = t & 63;
    int quad = l >> 4, col = l & 15;
    int wn = w >> 1, wc = w & 1;
    int c0 = (l & 31) * 8, nh = l >> 5;
    int sw = col & 7;

    bf16x8 bfr[16];
#pragma unroll
    for (int ck = 0; ck < 2; ++ck)
#pragma unroll
        for (int ks = 0; ks < 8; ++ks)
            bfr[ck * 8 + ks] = *(const bf16x8*)(W2p + ((((wc * 2 + ck) * 8 + ks) * 64 + l) * 8));

    f32x2 wgx2[4], wgy2[4]; float A_[8];
    prep_ctx(grid, W1, a1, c0, wgx2, wgy2, A_);

    // scratch-free grid-coef selects (all A_ reads const-indexed; w uniform, nh lane)
    float ax0 = (w & 2) ? ((w & 1) ? A_[6] : A_[4]) : ((w & 1) ? A_[2] : A_[0]);
    float ax1 = (w & 2) ? ((w & 1) ? A_[7] : A_[5]) : ((w & 1) ? A_[3] : A_[1]);
    f32x4 ay4;
    ay4[0] = nh ? A_[1] : A_[0];
    ay4[1] = nh ? A_[3] : A_[2];
    ay4[2] = nh ? A_[5] : A_[4];
    ay4[3] = nh ? A_[7] : A_[6];
    int nbase = w * 16 + nh;

    // hoist per-channel BN1 vectors out of stage16 (row-invariant)
    f32x4 va0 = *(const f32x4*)(a1 + c0), va1h = *(const f32x4*)(a1 + c0 + 4);
    f32x4 vd0 = *(const f32x4*)(d1 + c0), vd1h = *(const f32x4*)(d1 + c0 + 4);

    float s[2][4] = {}, q[2][4] = {};

    const float* tokbase = tokpart + (size_t)blockIdx.x * 8 * C_;
    // prologue: stage row 0 into buf0; then t0/t1 <- row 1
    {
        f32x4 p0 = *(const f32x4*)(tokbase + c0);
        f32x4 p1 = *(const f32x4*)(tokbase + c0 + 4);
        stage16(&y1[0][0], nbase, c0, va0, va1h, vd0, vd1h, wgx2, wgy2, ax0, ax1, ay4, p0, p1);
    }
    f32x4 t0 = *(const f32x4*)(tokbase + C_ + c0);
    f32x4 t1 = *(const f32x4*)(tokbase + C_ + c0 + 4);
    barrier_lgkm();

#pragma unroll 1
    for (int r8 = 0; r8 < 8; ++r8) {
        int row = blockIdx.x * 8 + r8;
        int cur = r8 & 1;
        // prefetch row r8+2 tok slice (consumed by next iteration's stage)
        int nr = (r8 < 6) ? (r8 + 2) : 7;
        f32x4 n0 = *(const f32x4*)(tokbase + (size_t)nr * C_ + c0);
        f32x4 n1 = *(const f32x4*)(tokbase + (size_t)nr * C_ + c0 + 4);

#pragma unroll
        for (int rt = 0; rt < 2; ++rt) {
            int rowb = (wn * 32 + rt * 16 + col) * 256;
            bf16x8 af[8];
#pragma unroll
            for (int ks = 0; ks < 8; ++ks)
                af[ks] = *(const bf16x8*)(&y1[cur][rowb + (((ks * 4 + quad) ^ sw) << 3)]);
#pragma unroll
            for (int ck = 0; ck < 2; ++ck) {
                f32x4 acc = {0.f, 0.f, 0.f, 0.f};
#pragma unroll
                for (int ks = 0; ks < 8; ++ks)
                    acc = __builtin_amdgcn_mfma_f32_16x16x32_bf16(bfr[ck * 8 + ks], af[ks], acc, 0, 0, 0);
#pragma unroll
                for (int rr = 0; rr < 4; ++rr) {
                    s[ck][rr] += acc[rr];
                    q[ck][rr] += acc[rr] * acc[rr];
                }
                if constexpr (SPILL) {
                    bf16x4 v; bf16x2* v2 = (bf16x2*)&v;
                    v2[0] = cvt2(acc[0], acc[1]);
                    v2[1] = cvt2(acc[2], acc[3]);
                    *(bf16x4*)(h2s + (size_t)row * 4096 +
                               ((wn * 2 + rt) * 4 + wc * 2 + ck) * 256 + l * 4) = v;
                }
            }
        }
        // stage next row into the other buffer — overlaps with MFMAs above.
        if (r8 < 7)
            stage16(&y1[cur ^ 1][0], nbase, c0, va0, va1h, vd0, vd1h,
                    wgx2, wgy2, ax0, ax1, ay4, t0, t1);
        barrier_lgkm();   // buf[cur^1] fully staged; everyone done reading buf[cur]
        t0 = n0; t1 = n1;
    }
    int slot = ((blockIdx.x << 1) | wn) & 63;
#pragma unroll
    for (int ck = 0; ck < 2; ++ck)
#pragma unroll
        for (int rr = 0; rr < 4; ++rr) {
            float sv = s[ck][rr], qv = q[ck][rr];
            sv += __shfl_xor(sv, 1, 64); sv += __shfl_xor(sv, 2, 64);
            sv += __shfl_xor(sv, 4, 64); sv += __shfl_xor(sv, 8, 64);
            qv += __shfl_xor(qv, 1, 64); qv += __shfl_xor(qv, 2, 64);
            qv += __shfl_xor(qv, 4, 64); qv += __shfl_xor(qv, 8, 64);
            if (col == 0) {
                int c2 = wc * 32 + ck * 16 + quad * 4 + rr;
                atomicAdd(p2s + slot * H2_ + c2, sv);
                atomicAdd(p2q + slot * H2_ + c2, qv);
            }
        }
}

// ---------------- K2b: BN2 params (raw-acc stats; b2 cancels) -----------------------
__global__ void k2b(const float* __restrict__ p2s, const float* __restrict__ p2q,
                    const float* __restrict__ gamma2, const float* __restrict__ beta2,
                    float* __restrict__ a2o, float* __restrict__ d2o) {
    int t = threadIdx.x;
    float S = 0.f, Q = 0.f;
#pragma unroll 8
    for (int s = 0; s < 64; ++s) { S += p2s[s * H2_ + t]; Q += p2q[s * H2_ + t]; }
    const float invN = 1.f / ((float)ROWS * 64.f);
    float mean = S * invN;
    float var = Q * invN - mean * mean;
    float a2 = gamma2[t] * rsqrtf(var + EPSN);
    a2o[t] = a2;
    d2o[t] = beta2[t] - a2 * mean;
}

// ---------------- K3 (spill path): barrier-free wave-private tiles (round-5) --------
__global__ __launch_bounds__(256) void k3s(const __bf16* __restrict__ h2s,
                                           const float* __restrict__ a2,
                                           const float* __restrict__ d2p,
                                           const __bf16* __restrict__ W3p,
                                           const float* __restrict__ b3,
                                           const float* __restrict__ coarse,
                                           float* __restrict__ fine) {
    __shared__ __align__(16) __bf16 y2l[4][16 * 64];    // 8192 B (per-wave 2 KB)
    __shared__ __align__(16) float finebuf[8 * 192];    // 6144 B
    int t = threadIdx.x, w = t >> 6, l = t & 63;
    int quad = l >> 4, col = l & 15;
    int sw = col & 7;

    bf16x8 wfr[2];
#pragma unroll
    for (int ks = 0; ks < 2; ++ks)
        wfr[ks] = *(const bf16x8*)(W3p + ((ks * 64 + l) * 8));

    float a2v[16], d2v[16];
#pragma unroll
    for (int ck = 0; ck < 4; ++ck)
#pragma unroll
        for (int rr = 0; rr < 4; ++rr) {
            int c2 = ck * 16 + quad * 4 + rr;
            a2v[ck * 4 + rr] = a2[c2];
            d2v[ck * 4 + rr] = d2p[c2];
        }
    float b3v = (col < 3) ? b3[col] : 0.f;
    __bf16* yw = &y2l[w][0];

#pragma unroll 1
    for (int r8 = 0; r8 < 8; ++r8) {
        int row = blockIdx.x * 8 + r8;
        const __bf16* src = h2s + (size_t)row * 4096 + l * 4;
        bf16x4 u[4];
#pragma unroll
        for (int ck = 0; ck < 4; ++ck)
            u[ck] = *(const bf16x4*)(src + (w * 4 + ck) * 256);
#pragma unroll
        for (int ck = 0; ck < 4; ++ck) {
            float y0 = fmaxf(fmaf(a2v[ck * 4 + 0], (float)u[ck][0], d2v[ck * 4 + 0]), 0.f);
            float y1v = fmaxf(fmaf(a2v[ck * 4 + 1], (float)u[ck][1], d2v[ck * 4 + 1]), 0.f);
            float y2 = fmaxf(fmaf(a2v[ck * 4 + 2], (float)u[ck][2], d2v[ck * 4 + 2]), 0.f);
            float y3 = fmaxf(fmaf(a2v[ck * 4 + 3], (float)u[ck][3], d2v[ck * 4 + 3]), 0.f);
            bf16x4 v; bf16x2* v2 = (bf16x2*)&v;
            v2[0] = cvt2(y0, y1v); v2[1] = cvt2(y2, y3);
            int chunk = ck * 2 + (quad >> 1);
            *(bf16x4*)(&yw[col * 64 + ((chunk ^ sw) << 3) + (quad & 1) * 4]) = v;
        }
        // same-wave lgkm ordering; no barrier
        bf16x8 af2[2];
#pragma unroll
        for (int ks = 0; ks < 2; ++ks)
            af2[ks] = *(const bf16x8*)(&yw[col * 64 + (((ks * 4 + quad) ^ sw) << 3)]);
        f32x4 acc = {0.f, 0.f, 0.f, 0.f};
        acc = __builtin_amdgcn_mfma_f32_16x16x32_bf16(af2[0], wfr[0], acc, 0, 0, 0);
        acc = __builtin_amdgcn_mfma_f32_16x16x32_bf16(af2[1], wfr[1], acc, 0, 0, 0);
        if (col < 3) {
            float cj = coarse[row * 3 + col] + b3v;
#pragma unroll
            for (int rr = 0; rr < 4; ++rr)
                finebuf[r8 * 192 + (w * 16 + quad * 4 + rr) * 3 + col] = acc[rr] + cj;
        }
    }
    __syncthreads();
    {
        float* dst = fine + (size_t)blockIdx.x * 1536;
        const f32x4* fb = (const f32x4*)finebuf;
        *(f32x4*)(dst + 4 * t) = fb[t];
        if (t < 128) *(f32x4*)(dst + 1024 + 4 * t) = fb[256 + t];
    }
}

// ---------------- K3 (fallback): recompute y1 + GEMM2, BN2+ReLU, GEMM3, fine --------
__global__ __launch_bounds__(256) void k3r(const float* __restrict__ tokpart,
                                           const float* __restrict__ grid,
                                           const float* __restrict__ W1,
                                           const __bf16* __restrict__ W2p,
                                           const float* __restrict__ a1,
                                           const float* __restrict__ d1,
                                           const __bf16* __restrict__ W3p,
                                           const float* __restrict__ a2,
                                           const float* __restrict__ d2p,
                                           const float* __restrict__ b3,
                                           const float* __restrict__ coarse,
                                           float* __restrict__ fine) {
    __shared__ __align__(16) __bf16 y1[64 * 256];
    __shared__ __align__(16) __bf16 y2l[64 * 72];
    __shared__ __align__(16) float finebuf[8 * 192];
    int t = threadIdx.x, w = t >> 6, l = t & 63;
    int quad = l >> 4, col = l & 15;
    int wn = w >> 1, wc = w & 1;
    int c0 = (l & 31) * 8, nh = l >> 5;
    int sw = col & 7;

    bf16x8 bfr[16];
#pragma unroll
    for (int ck = 0; ck < 2; ++ck)
#pragma unroll
        for (int ks = 0; ks < 8; ++ks)
            bfr[ck * 8 + ks] = *(const bf16x8*)(W2p + ((((wc * 2 + ck) * 8 + ks) * 64 + l) * 8));
    bf16x8 wfr[2];
#pragma unroll
    for (int ks = 0; ks < 2; ++ks)
        wfr[ks] = *(const bf16x8*)(W3p + ((ks * 64 + l) * 8));

    f32x2 wgx2[4], wgy2[4]; float A_[8];
    prep_ctx(grid, W1, a1, c0, wgx2, wgy2, A_);

    float ax0 = (w & 2) ? ((w & 1) ? A_[6] : A_[4]) : ((w & 1) ? A_[2] : A_[0]);
    float ax1 = (w & 2) ? ((w & 1) ? A_[7] : A_[5]) : ((w & 1) ? A_[3] : A_[1]);
    f32x4 ay4;
    ay4[0] = nh ? A_[1] : A_[0];
    ay4[1] = nh ? A_[3] : A_[2];
    ay4[2] = nh ? A_[5] : A_[4];
    ay4[3] = nh ? A_[7] : A_[6];
    int nbase = w * 16 + nh;

    f32x4 va0 = *(const f32x4*)(a1 + c0), va1h = *(const f32x4*)(a1 + c0 + 4);
    f32x4 vd0 = *(const f32x4*)(d1 + c0), vd1h = *(const f32x4*)(d1 + c0 + 4);

    float a2v[8], d2v[8];
#pragma unroll
    for (int ck = 0; ck < 2; ++ck)
#pragma unroll
        for (int rr = 0; rr < 4; ++rr) {
            int c2 = wc * 32 + ck * 16 + quad * 4 + rr;
            a2v[ck * 4 + rr] = a2[c2];
            d2v[ck * 4 + rr] = d2p[c2];
        }
    float b3v = (col < 3) ? b3[col] : 0.f;

    const float* tokbase = tokpart + (size_t)blockIdx.x * 8 * C_;
    f32x4 t0 = *(const f32x4*)(tokbase + c0);
    f32x4 t1 = *(const f32x4*)(tokbase + c0 + 4);

#pragma unroll 1
    for (int r8 = 0; r8 < 8; ++r8) {
        int row = blockIdx.x * 8 + r8;
        int nr = (r8 < 7) ? (r8 + 1) : 7;
        f32x4 n0 = *(const f32x4*)(tokbase + (size_t)nr * C_ + c0);
        f32x4 n1 = *(const f32x4*)(tokbase + (size_t)nr * C_ + c0 + 4);

        stage16(y1, nbase, c0, va0, va1h, vd0, vd1h, wgx2, wgy2, ax0, ax1, ay4, t0, t1);
        barrier_lgkm();
#pragma unroll
        for (int rt = 0; rt < 2; ++rt) {
            int rowb = (wn * 32 + rt * 16 + col) * 256;
            bf16x8 af[8];
#pragma unroll
            for (int ks = 0; ks < 8; ++ks)
                af[ks] = *(const bf16x8*)(&y1[rowb + (((ks * 4 + quad) ^ sw) << 3)]);
#pragma unroll
            for (int ck = 0; ck < 2; ++ck) {
                f32x4 acc = {0.f, 0.f, 0.f, 0.f};
#pragma unroll
                for (int ks = 0; ks < 8; ++ks)
                    acc = __builtin_amdgcn_mfma_f32_16x16x32_bf16(bfr[ck * 8 + ks], af[ks], acc, 0, 0, 0);
                bf16x4 v; bf16x2* v2 = (bf16x2*)&v;
                float y0 = fmaxf(fmaf(a2v[ck * 4 + 0], acc[0], d2v[ck * 4 + 0]), 0.f);
                float y1v = fmaxf(fmaf(a2v[ck * 4 + 1], acc[1], d2v[ck * 4 + 1]), 0.f);
                float y2 = fmaxf(fmaf(a2v[ck * 4 + 2], acc[2], d2v[ck * 4 + 2]), 0.f);
                float y3 = fmaxf(fmaf(a2v[ck * 4 + 3], acc[3], d2v[ck * 4 + 3]), 0.f);
                v2[0] = cvt2(y0, y1v); v2[1] = cvt2(y2, y3);
                *(bf16x4*)(&y2l[(wn * 32 + rt * 16 + col) * 72 + wc * 32 + ck * 16 + quad * 4]) = v;
            }
        }
        barrier_lgkm();
        bf16x8 af2[2];
#pragma unroll
        for (int ks = 0; ks < 2; ++ks)
            af2[ks] = *(const bf16x8*)(&y2l[(w * 16 + col) * 72 + ks * 32 + quad * 8]);
        f32x4 d2acc = {0.f, 0.f, 0.f, 0.f};
        d2acc = __builtin_amdgcn_mfma_f32_16x16x32_bf16(af2[0], wfr[0], d2acc, 0, 0, 0);
        d2acc = __builtin_amdgcn_mfma_f32_16x16x32_bf16(af2[1], wfr[1], d2acc, 0, 0, 0);
        if (col < 3) {
            float cj = coarse[row * 3 + col] + b3v;
#pragma unroll
            for (int rr = 0; rr < 4; ++rr)
                finebuf[r8 * 192 + (w * 16 + quad * 4 + rr) * 3 + col] = d2acc[rr] + cj;
        }
        barrier_lgkm();
        t0 = n0; t1 = n1;
    }
    {
        float* dst = fine + (size_t)blockIdx.x * 1536;
        const f32x4* fb = (const f32x4*)finebuf;
        *(f32x4*)(dst + 4 * t) = fb[t];
        if (t < 128) *(f32x4*)(dst + 1024 + 4 * t) = fb[256 + t];
    }
}

// ---------------- host launcher -----------------------------------------------------
extern "C" void kernel_launch(void* const* d_in, const int* in_sizes, int n_in,
                              void* d_out, int out_size, void* d_ws, size_t ws_size,
                              hipStream_t stream) {
    (void)in_sizes; (void)n_in; (void)out_size;
    const float* tokens = (const float*)d_in[0];
    const float* grid   = (const float*)d_in[1];
    const float* Wc     = (const float*)d_in[2];
    const float* bc     = (const float*)d_in[3];
    const float* W1     = (const float*)d_in[4];
    const float* gamma1 = (const float*)d_in[6];
    const float* beta1  = (const float*)d_in[7];
    const float* W2     = (const float*)d_in[8];
    const float* gamma2 = (const float*)d_in[10];
    const float* beta2  = (const float*)d_in[11];
    const float* W3     = (const float*)d_in[12];
    const float* b3     = (const float*)d_in[13];

    char* ws = (char*)d_ws;
    __bf16* W1p     = (__bf16*)(ws);                     // 131072 B
    __bf16* W2p     = (__bf16*)(ws + 131072);            //  32768 B
    float*  p1s     = (float*)(ws + 163840);             //  32768 B (zeroed by k0)
    float*  p1q     = (float*)(ws + 196608);             //  32768 B (zeroed by k0)
    float*  p2s     = (float*)(ws + 229376);             //  16384 B (zeroed by k0)
    float*  p2q     = (float*)(ws + 245760);             //  16384 B (zeroed by k0)
    float*  a1      = (float*)(ws + 262144);             //   1024 B
    float*  d1      = (float*)(ws + 263168);             //   1024 B
    float*  a2      = (float*)(ws + 264192);             //    256 B
    float*  d2p     = (float*)(ws + 264448);             //    256 B
    __bf16* W3p     = (__bf16*)(ws + 264704);            //   2048 B
    __bf16* Wcp     = (__bf16*)(ws + 266752);            //   8192 B
    float*  gm      = (float*)(ws + 274944);             //   1024 B
    float*  gvv     = (float*)(ws + 275968);             //   1024 B
    float*  tokpart = (float*)(ws + 276992);             // 16777216 B
    __bf16* h2s     = (__bf16*)(ws + 17054208);          // 134217728 B (if it fits)

    const size_t SPILL_NEED = 17054208ull + 134217728ull;  // 151271936
    bool spill = ws_size >= SPILL_NEED;

    float* coarse = (float*)d_out;
    float* fine   = (float*)d_out + (size_t)ROWS * 3;

    k0_pack<<<320, 256, 0, stream>>>(W1, W2, W3, Wc, grid, W1p, W2p, W3p, Wcp,
                                     p1s, gm, gvv);
    k1a<<<512, 256, 0, stream>>>(tokens, W1p, Wcp, bc, tokpart, coarse, p1s, p1q);
    k1b<<<1, 256, 0, stream>>>(gm, gvv, gamma1, beta1, p1s, p1q, a1, d1);
    if (spill) {
        k2<true><<<ROWS / 8, 256, 0, stream>>>(tokpart, grid, W1, W2p, a1, d1,
                                               p2s, p2q, h2s);
        k2b<<<1, 64, 0, stream>>>(p2s, p2q, gamma2, beta2, a2, d2p);
        k3s<<<ROWS / 8, 256, 0, stream>>>(h2s, a2, d2p, W3p, b3, coarse, fine);
    } else {
        k2<false><<<ROWS / 8, 256, 0, stream>>>(tokpart, grid, W1, W2p, a1, d1,
                                                p2s, p2q, h2s);
        k2b<<<1, 64, 0, stream>>>(p2s, p2q, gamma2, beta2, a2, d2p);
        k3r<<<ROWS / 8, 256, 0, stream>>>(tokpart, grid, W1, W2p, a1, d1,
                                          W3p, a2, d2p, b3, coarse, fine);
    }
}